// Round 9
// baseline (1130.031 us; speedup 1.0000x reference)
//
#include <hip/hip_runtime.h>
#include <math.h>

#define DMODEL 1024
#define NHEADS 16
#define DHEAD  64
#define BATCH  2
#define SEQ    2048
#define NTOK   (BATCH*SEQ)            // 4096
#define WEL    (DMODEL*DMODEL)        // 1048576
#define PLANE  ((size_t)NTOK*DMODEL)  // 4,194,304 B per digit plane

typedef double v4d __attribute__((ext_vector_type(4)));
typedef int    v4i __attribute__((ext_vector_type(4)));

#define OFF_TERN 4096
#define OFF_XD   (OFF_TERN + 4*WEL)
#define OFF_QDF  (OFF_XD  + 5*4194304)
#define OFF_KDF  (OFF_QDF + 20971520)
#define OFF_VDF  (OFF_KDF + 20971520)
#define WS_NEED  ((size_t)OFF_VDF + 20971520)

#define TWO36 68719476736.0
#define LOG2E 1.4426950408889634

__global__ void k_zero_scalars(double* S) {
    if (threadIdx.x < 64) S[threadIdx.x] = 0.0;
}

__device__ __forceinline__ double block_reduce_sum(double v, double* red) {
    int tid = threadIdx.x;
    __syncthreads();
    red[tid] = v;
    __syncthreads();
    for (int s = 128; s > 0; s >>= 1) {
        if (tid < s) red[tid] += red[tid + s];
        __syncthreads();
    }
    return red[0];
}

__global__ __launch_bounds__(256) void k_abssum(
    const float* __restrict__ W0, const float* __restrict__ W1,
    const float* __restrict__ W2, const float* __restrict__ W3, double* S) {
    __shared__ double red[256];
    int w = blockIdx.y;
    const float* W = (w == 0) ? W0 : (w == 1) ? W1 : (w == 2) ? W2 : W3;
    double s = 0.0;
    for (int i = blockIdx.x * 256 + threadIdx.x; i < WEL; i += 256 * 256)
        s += fabs((double)W[i]);
    double bs = block_reduce_sum(s, red);
    if (threadIdx.x == 0) atomicAdd(&S[w], bs);
}

__global__ void k_delta(double* S) {
    int w = threadIdx.x;
    if (w < 4) S[16 + w] = 0.05 * S[w] / (double)WEL;
}

__global__ __launch_bounds__(256) void k_tern(
    const float* __restrict__ W0, const float* __restrict__ W1,
    const float* __restrict__ W2, const float* __restrict__ W3,
    signed char* __restrict__ tern, double* S) {
    __shared__ double red[256];
    int w = blockIdx.y;
    const float* W = (w == 0) ? W0 : (w == 1) ? W1 : (w == 2) ? W2 : W3;
    signed char* t = tern + (size_t)w * WEL;
    double delta = S[16 + w];
    double ms = 0.0, mc = 0.0;
    for (int i = blockIdx.x * 256 + threadIdx.x; i < WEL; i += 256 * 256) {
        float wv = W[i];
        double a = fabs((double)wv);
        bool m = a > delta;
        t[i] = m ? (wv > 0.0f ? (signed char)1 : (signed char)-1) : (signed char)0;
        if (m) { ms += a; mc += 1.0; }
    }
    double bms = block_reduce_sum(ms, red);
    double bmc = block_reduce_sum(mc, red);
    if (threadIdx.x == 0) { atomicAdd(&S[4 + w], bms); atomicAdd(&S[8 + w], bmc); }
}

__global__ void k_alpha(double* S) {
    int w = threadIdx.x;
    if (w < 4) S[12 + w] = S[4 + w] / fmax(S[8 + w], 1.0);
}

__global__ __launch_bounds__(256) void k_digx(const float* __restrict__ x,
                                              signed char* __restrict__ XD) {
    int g = blockIdx.x * 256 + threadIdx.x;
    const int NG = NTOK * DMODEL / 4;
    if (g >= NG) return;
    float4 f = ((const float4*)x)[g];
    double vals[4] = {f.x, f.y, f.z, f.w};
    unsigned int p[5] = {0, 0, 0, 0, 0};
#pragma unroll
    for (int e = 0; e < 4; ++e) {
        long X = llrint(vals[e] * TWO36);
        const long LIM = (1L << 39) - 1;
        X = (X > LIM) ? LIM : (X < -LIM ? -LIM : X);
#pragma unroll
        for (int i = 0; i < 5; ++i) {
            signed char di = (signed char)X;
            X = (X - di) >> 8;
            p[i] |= ((unsigned int)(unsigned char)di) << (8 * e);
        }
    }
#pragma unroll
    for (int i = 0; i < 5; ++i)
        ((unsigned int*)(XD + (size_t)i * PLANE))[g] = p[i];
}

// ---------------- QKV projection (round-5 proven, unchanged) ----------------
__global__ __launch_bounds__(256) void k_proji8(
    const signed char* __restrict__ XD, const signed char* __restrict__ tern,
    const float* __restrict__ bq, const float* __restrict__ bk,
    const float* __restrict__ bv,
    unsigned char* __restrict__ QDF, unsigned char* __restrict__ KDF,
    unsigned char* __restrict__ VDF, const double* __restrict__ S) {
    int w = blockIdx.z;
    const signed char* B = tern + (size_t)w * WEL;
    const float* bias = (w == 0) ? bq : (w == 1) ? bk : bv;
    double alpha = S[12 + w];

    __shared__ signed char As[128 * 144];
    __shared__ signed char Bs[64 * 144];

    int tid = threadIdx.x;
    int wv = tid >> 6, l = tid & 63, lm = l & 15, lk = l >> 4;
    int wy = wv >> 1, wx = wv & 1;
    int row0 = blockIdx.x * 128, col0 = blockIdx.y * 64;

    v4i zz4 = {0, 0, 0, 0};
    long ppa = (lk == 0) ? (long)lm : 0L;
    long ppb = (lk == 0) ? 1L : 0L;
    v4i rowv = __builtin_amdgcn_mfma_i32_16x16x32_i8(ppa, ppb, zz4, 0, 0, 0);
    v4i colv = __builtin_amdgcn_mfma_i32_16x16x32_i8(ppb, ppa, zz4, 0, 0, 0);
    int rowi[4];
#pragma unroll
    for (int j = 0; j < 4; ++j) rowi[j] = rowv[j];
    int coli = colv[0];

    v4d Facc[8];
#pragma unroll
    for (int t = 0; t < 8; ++t) Facc[t] = (v4d){0.0, 0.0, 0.0, 0.0};

    const double DW[5] = {0x1p-36, 0x1p-28, 0x1p-20, 0x1p-12, 0x1p-4};

    for (int d = 0; d < 5; ++d) {
        const signed char* Ad = XD + (size_t)d * PLANE;
        v4i Iacc[8];
#pragma unroll
        for (int t = 0; t < 8; ++t) Iacc[t] = (v4i){0, 0, 0, 0};

        for (int k0 = 0; k0 < DMODEL; k0 += 128) {
            __syncthreads();
            {
                int r = tid >> 1, hf = tid & 1;
                const int4* src = (const int4*)(Ad + (size_t)(row0 + r) * DMODEL + k0 + hf * 64);
                int4* dst = (int4*)(As + r * 144 + hf * 64);
                dst[0] = src[0]; dst[1] = src[1]; dst[2] = src[2]; dst[3] = src[3];
            }
            {
                int r = tid >> 2, q = tid & 3;
                const int4* src = (const int4*)(B + (size_t)(col0 + r) * DMODEL + k0 + q * 32);
                int4* dst = (int4*)(Bs + r * 144 + q * 32);
                dst[0] = src[0]; dst[1] = src[1];
            }
            __syncthreads();
#pragma unroll
            for (int ks = 0; ks < 4; ++ks) {
                long av[4], bv2[2];
#pragma unroll
                for (int mt = 0; mt < 4; ++mt)
                    av[mt] = *(const long*)(As + (wy * 64 + mt * 16 + lm) * 144 + ks * 32 + 8 * lk);
#pragma unroll
                for (int nt = 0; nt < 2; ++nt)
                    bv2[nt] = *(const long*)(Bs + (wx * 32 + nt * 16 + lm) * 144 + ks * 32 + 8 * lk);
#pragma unroll
                for (int mt = 0; mt < 4; ++mt)
#pragma unroll
                    for (int nt = 0; nt < 2; ++nt)
                        Iacc[mt * 2 + nt] = __builtin_amdgcn_mfma_i32_16x16x32_i8(
                            av[mt], bv2[nt], Iacc[mt * 2 + nt], 0, 0, 0);
            }
        }
        double wd = DW[d];
#pragma unroll
        for (int t = 0; t < 8; ++t)
#pragma unroll
            for (int j = 0; j < 4; ++j) Facc[t][j] += wd * (double)Iacc[t][j];
    }

#pragma unroll
    for (int t = 0; t < 8; ++t) {
#pragma unroll
        for (int j = 0; j < 4; ++j) {
            int rl = wy * 64 + (t >> 1) * 16 + rowi[j];
            int cl = wx * 32 + (t & 1) * 16 + coli;
            int n = row0 + rl, c = col0 + cl;
            double v = alpha * Facc[t][j] + (double)bias[c];
            long X = llrint(v * TWO36);
            const long LIM = (1L << 39) - 1;
            X = (X > LIM) ? LIM : (X < -LIM ? -LIM : X);
            int bh = ((n >> 11) << 4) + (c >> 6);
            int d = c & 63;
            int t2 = n & 2047;
            size_t base; size_t pstride;
            if (w == 0) {
                int rg = t2 >> 4, m = t2 & 15;
                int kc = d >> 5, k32 = d & 31, lkq = k32 >> 3, e = k32 & 7;
                base = ((size_t)(bh * 128 + rg) * 5) * 1024 + (size_t)kc * 512
                     + (16 * lkq + m) * 8 + e;
                pstride = 1024;
            } else if (w == 1) {
                int s5 = t2 >> 6, s64 = t2 & 63, ct = s64 >> 4, nn = s64 & 15;
                int kc = d >> 5, k32 = d & 31, lkq = k32 >> 3, e = k32 & 7;
                base = (size_t)(bh * 32 + s5) * 20480 + (size_t)(ct * 2 + kc) * 512
                     + (16 * lkq + nn) * 8 + e;
                pstride = 4096;
            } else {
                int s5 = t2 >> 6, s64 = t2 & 63;
                int ks = 4 * (s64 & 15) + (s64 >> 4);
                int kc2 = ks >> 5, k32 = ks & 31, lkq = k32 >> 3, e = k32 & 7;
                int u = d >> 4, lmv = d & 15;
                base = (size_t)(bh * 32 + s5) * 20480 + (size_t)(u * 2 + kc2) * 512
                     + (16 * lkq + lmv) * 8 + e;
                pstride = 4096;
            }
            unsigned char* P = (w == 0) ? QDF : (w == 1) ? KDF : VDF;
#pragma unroll
            for (int i = 0; i < 5; ++i) {
                signed char di = (signed char)X;
                X = (X - di) >> 8;
                P[base + (size_t)i * pstride] = di;
            }
        }
    }
}

// fast e^x via 2^t table+poly. x <= 0 required (clamped at -600 natural).
__device__ __forceinline__ double fexp(double x, const double* Texp) {
    double t = fmax(x, -600.0) * LOG2E;
    double f = rint(t * 16.0);
    double r = t - f * 0.0625;                      // exact
    double u = r * 0.6931471805599453;
    double poly = 1.0 + u * (1.0 + u * (0.5 + u * (1.0 / 6.0 +
                  u * (1.0 / 24.0 + u * (1.0 / 120.0)))));
    int fi = (int)f;
    double sp = __longlong_as_double((long)(1023 + (fi >> 4)) << 52);  // 2^(fi>>4)
    return Texp[fi & 15] * poly * sp;
}

// ---------------- all-i8 flash attention: round-5 staging + fexp softmax ----------
// NOTE: round 6-8's K/V register prefetch REMOVED — suspected VMEM/LDS
// write-after-read hazard corrupting staged tiles (bisection evidence:
// error insensitive to entire softmax/digitize path).
__global__ __launch_bounds__(256, 2) void k_attn(
    const unsigned char* __restrict__ QDF, const unsigned char* __restrict__ KDF,
    const unsigned char* __restrict__ VDF, signed char* __restrict__ YD) {
    __shared__ unsigned long KBs[2560];
    __shared__ unsigned long VBs[2560];
    __shared__ signed char  PD[4 * 5 * 16 * 72];
    __shared__ double Texp[16];

    int tid = threadIdx.x;
    int w = tid >> 6, l = tid & 63;
    int lm = l & 15, lk = l >> 4;
    int bh = blockIdx.y;
    int t0 = blockIdx.x * 64;
    size_t nrow0 = (size_t)(bh >> 4) * SEQ;
    int cbase = (bh & 15) * 64;

    if (tid < 16) Texp[tid] = exp2((double)tid * 0.0625);

    v4i zz4 = {0, 0, 0, 0};
    long ppa = (lk == 0) ? (long)lm : 0L;
    long ppb = (lk == 0) ? 1L : 0L;
    v4i rowv = __builtin_amdgcn_mfma_i32_16x16x32_i8(ppa, ppb, zz4, 0, 0, 0);
    v4i colv = __builtin_amdgcn_mfma_i32_16x16x32_i8(ppb, ppa, zz4, 0, 0, 0);
    int rowi[4];
#pragma unroll
    for (int j = 0; j < 4; ++j) rowi[j] = rowv[j];
    int coli = colv[0];

    unsigned long qf[5][2];
    {
        size_t rg5 = ((size_t)bh * 128 + (t0 >> 4) + w) * 5;
#pragma unroll
        for (int p = 0; p < 5; ++p)
#pragma unroll
            for (int kc = 0; kc < 2; ++kc)
                qf[p][kc] = *(const unsigned long*)(QDF + (rg5 + p) * 1024 + kc * 512 + l * 8);
    }

    double m_[4], l_[4];
    v4d Yacc[4];
#pragma unroll
    for (int j = 0; j < 4; j++) { m_[j] = -1.0e6; l_[j] = 0.0; }
#pragma unroll
    for (int u = 0; u < 4; u++) Yacc[u] = (v4d){0.0, 0.0, 0.0, 0.0};

    size_t kvbase = (size_t)bh * 32 * 20480;

    for (int s5 = 0; s5 < 32; ++s5) {
        __syncthreads();
        {
            const int4* gk = (const int4*)(KDF + kvbase + (size_t)s5 * 20480);
            const int4* gv = (const int4*)(VDF + kvbase + (size_t)s5 * 20480);
            int4* dk = (int4*)KBs;
            int4* dv = (int4*)VBs;
#pragma unroll
            for (int it = 0; it < 5; ++it) {
                dk[it * 256 + tid] = gk[it * 256 + tid];
                dv[it * 256 + tid] = gv[it * 256 + tid];
            }
        }
        __syncthreads();

        double sv[4][4];   // [c][j]: scores (natural units, /8), then p

        // ---- QK^T: pairs i+j>=3, exact i32 levels, i64 Horner ----
#pragma unroll
        for (int h2 = 0; h2 < 2; ++h2) {
            v4i lev[6][2];
#pragma unroll
            for (int L = 0; L < 6; ++L) { lev[L][0] = zz4; lev[L][1] = zz4; }
#pragma unroll
            for (int kc = 0; kc < 2; ++kc)
#pragma unroll
                for (int j = 0; j < 5; ++j) {
                    unsigned long b0 = KBs[((j * 4 + h2 * 2 + 0) * 2 + kc) * 64 + l];
                    unsigned long b1 = KBs[((j * 4 + h2 * 2 + 1) * 2 + kc) * 64 + l];
#pragma unroll
                    for (int i = 0; i < 5; ++i)
                        if (i + j >= 3) {
                            int L = i + j - 3;
                            lev[L][0] = __builtin_amdgcn_mfma_i32_16x16x32_i8(
                                (long)qf[i][kc], (long)b0, lev[L][0], 0, 0, 0);
                            lev[L][1] = __builtin_amdgcn_mfma_i32_16x16x32_i8(
                                (long)qf[i][kc], (long)b1, lev[L][1], 0, 0, 0);
                        }
                }
#pragma unroll
            for (int cc2 = 0; cc2 < 2; ++cc2)
#pragma unroll
                for (int j2 = 0; j2 < 4; ++j2) {
                    long acc = (long)lev[5][cc2][j2];
#pragma unroll
                    for (int L = 4; L >= 0; --L) acc = (acc << 8) + (long)lev[L][cc2][j2];
                    sv[h2 * 2 + cc2][j2] = (double)acc * 0x1p-51;  // *2^-48 * 0.125
                }
        }

        // ---- online softmax (fexp) + digitize P ----
#pragma unroll
        for (int j2 = 0; j2 < 4; ++j2) {
            double mt = fmax(fmax(sv[0][j2], sv[1][j2]), fmax(sv[2][j2], sv[3][j2]));
            mt = fmax(mt, __shfl_xor(mt, 1));
            mt = fmax(mt, __shfl_xor(mt, 2));
            mt = fmax(mt, __shfl_xor(mt, 4));
            mt = fmax(mt, __shfl_xor(mt, 8));
            double mn = fmax(m_[j2], mt);
            double cc_ = fexp(m_[j2] - mn, Texp);
            m_[j2] = mn;
            l_[j2] *= cc_;
#pragma unroll
            for (int u = 0; u < 4; ++u) Yacc[u][j2] *= cc_;
            double rs = 0.0;
#pragma unroll
            for (int c = 0; c < 4; ++c) {
                double p = fexp(sv[c][j2] - mn, Texp);
                sv[c][j2] = p;
                rs += p;
            }
            rs += __shfl_xor(rs, 1);
            rs += __shfl_xor(rs, 2);
            rs += __shfl_xor(rs, 4);
            rs += __shfl_xor(rs, 8);
            l_[j2] += rs;

            long X[4];
#pragma unroll
            for (int c = 0; c < 4; ++c) X[c] = llrint(sv[c][j2] * TWO36);
            int rbase = (w * 5 * 16 + rowi[j2]) * 72 + 4 * coli;
#pragma unroll
            for (int p = 0; p < 5; ++p) {
                unsigned int word = 0;
#pragma unroll
                for (int c = 0; c < 4; ++c) {
                    signed char di = (signed char)X[c];
                    X[c] = (X[c] - di) >> 8;
                    word |= ((unsigned int)(unsigned char)di) << (8 * c);
                }
                *(unsigned int*)(PD + rbase + p * 16 * 72) = word;
            }
        }

        // ---- PV: pairs i+j>=3, i64 Horner, scale 2^-48 ----
#pragma unroll
        for (int u2 = 0; u2 < 2; ++u2) {
            v4i lev[6][2];
#pragma unroll
            for (int L = 0; L < 6; ++L) { lev[L][0] = zz4; lev[L][1] = zz4; }
#pragma unroll
            for (int kc2 = 0; kc2 < 2; ++kc2) {
                long pa5[5];
#pragma unroll
                for (int i = 0; i < 5; ++i)
                    pa5[i] = *(const long*)(PD + ((w * 5 + i) * 16 + lm) * 72 + 32 * kc2 + 8 * lk);
#pragma unroll
                for (int j = 0; j < 5; ++j) {
                    unsigned long b0 = VBs[((j * 4 + u2 * 2 + 0) * 2 + kc2) * 64 + l];
                    unsigned long b1 = VBs[((j * 4 + u2 * 2 + 1) * 2 + kc2) * 64 + l];
#pragma unroll
                    for (int i = 0; i < 5; ++i)
                        if (i + j >= 3) {
                            int L = i + j - 3;
                            lev[L][0] = __builtin_amdgcn_mfma_i32_16x16x32_i8(
                                pa5[i], (long)b0, lev[L][0], 0, 0, 0);
                            lev[L][1] = __builtin_amdgcn_mfma_i32_16x16x32_i8(
                                pa5[i], (long)b1, lev[L][1], 0, 0, 0);
                        }
                }
            }
#pragma unroll
            for (int uu = 0; uu < 2; ++uu)
#pragma unroll
                for (int j2 = 0; j2 < 4; ++j2) {
                    long acc = (long)lev[5][uu][j2];
#pragma unroll
                    for (int L = 4; L >= 0; --L) acc = (acc << 8) + (long)lev[L][uu][j2];
                    Yacc[u2 * 2 + uu][j2] = fma((double)acc, 0x1p-48, Yacc[u2 * 2 + uu][j2]);
                }
        }
    }

    // ---- epilogue: y -> digit planes (row-major, for oproj) ----
#pragma unroll
    for (int j2 = 0; j2 < 4; ++j2) {
        double inv = 1.0 / l_[j2];
        size_t n = nrow0 + t0 + 16 * w + rowi[j2];
#pragma unroll
        for (int u = 0; u < 4; ++u) {
            double y = Yacc[u][j2] * inv;
            int c = cbase + 16 * u + coli;
            long X = llrint(y * TWO36);
            const long LIM = (1L << 39) - 1;
            X = (X > LIM) ? LIM : (X < -LIM ? -LIM : X);
#pragma unroll
            for (int i = 0; i < 5; ++i) {
                signed char di = (signed char)X;
                X = (X - di) >> 8;
                YD[(size_t)i * PLANE + n * DMODEL + c] = di;
            }
        }
    }
}

// ---------------- output projection (round-5 proven, unchanged) ----------------
__global__ __launch_bounds__(256) void k_oproji8(
    const signed char* __restrict__ YD, const signed char* __restrict__ tern,
    const float* __restrict__ bo, double* __restrict__ Z, double* __restrict__ S) {
    const signed char* B = tern + 3 * (size_t)WEL;
    double alpha = S[15];

    __shared__ signed char As[128 * 144];
    __shared__ signed char Bs[64 * 144];
    __shared__ double redm[256];

    int tid = threadIdx.x;
    int wv = tid >> 6, l = tid & 63, lm = l & 15, lk = l >> 4;
    int wy = wv >> 1, wx = wv & 1;
    int row0 = blockIdx.x * 128, col0 = blockIdx.y * 64;

    v4i zz4 = {0, 0, 0, 0};
    long ppa = (lk == 0) ? (long)lm : 0L;
    long ppb = (lk == 0) ? 1L : 0L;
    v4i rowv = __builtin_amdgcn_mfma_i32_16x16x32_i8(ppa, ppb, zz4, 0, 0, 0);
    v4i colv = __builtin_amdgcn_mfma_i32_16x16x32_i8(ppb, ppa, zz4, 0, 0, 0);
    int rowi[4];
#pragma unroll
    for (int j = 0; j < 4; ++j) rowi[j] = rowv[j];
    int coli = colv[0];

    v4d Facc[8];
#pragma unroll
    for (int t = 0; t < 8; ++t) Facc[t] = (v4d){0.0, 0.0, 0.0, 0.0};

    const double DW[5] = {0x1p-36, 0x1p-28, 0x1p-20, 0x1p-12, 0x1p-4};

    for (int d = 0; d < 5; ++d) {
        const signed char* Ad = YD + (size_t)d * PLANE;
        v4i Iacc[8];
#pragma unroll
        for (int t = 0; t < 8; ++t) Iacc[t] = (v4i){0, 0, 0, 0};

        for (int k0 = 0; k0 < DMODEL; k0 += 128) {
            __syncthreads();
            {
                int r = tid >> 1, hf = tid & 1;
                const int4* src = (const int4*)(Ad + (size_t)(row0 + r) * DMODEL + k0 + hf * 64);
                int4* dst = (int4*)(As + r * 144 + hf * 64);
                dst[0] = src[0]; dst[1] = src[1]; dst[2] = src[2]; dst[3] = src[3];
            }
            {
                int r = tid >> 2, q = tid & 3;
                const int4* src = (const int4*)(B + (size_t)(col0 + r) * DMODEL + k0 + q * 32);
                int4* dst = (int4*)(Bs + r * 144 + q * 32);
                dst[0] = src[0]; dst[1] = src[1];
            }
            __syncthreads();
#pragma unroll
            for (int ks = 0; ks < 4; ++ks) {
                long av[4], bv2[2];
#pragma unroll
                for (int mt = 0; mt < 4; ++mt)
                    av[mt] = *(const long*)(As + (wy * 64 + mt * 16 + lm) * 144 + ks * 32 + 8 * lk);
#pragma unroll
                for (int nt = 0; nt < 2; ++nt)
                    bv2[nt] = *(const long*)(Bs + (wx * 32 + nt * 16 + lm) * 144 + ks * 32 + 8 * lk);
#pragma unroll
                for (int mt = 0; mt < 4; ++mt)
#pragma unroll
                    for (int nt = 0; nt < 2; ++nt)
                        Iacc[mt * 2 + nt] = __builtin_amdgcn_mfma_i32_16x16x32_i8(
                            av[mt], bv2[nt], Iacc[mt * 2 + nt], 0, 0, 0);
            }
        }
        double wd = DW[d];
#pragma unroll
        for (int t = 0; t < 8; ++t)
#pragma unroll
            for (int j = 0; j < 4; ++j) Facc[t][j] += wd * (double)Iacc[t][j];
    }

    double mx = 0.0;
#pragma unroll
    for (int t = 0; t < 8; ++t) {
#pragma unroll
        for (int j = 0; j < 4; ++j) {
            int rl = wy * 64 + (t >> 1) * 16 + rowi[j];
            int cl = wx * 32 + (t & 1) * 16 + coli;
            int n = row0 + rl, c = col0 + cl;
            double v = alpha * Facc[t][j] + (double)bo[c];
            Z[(size_t)n * DMODEL + c] = v;
            mx = fmax(mx, fabs(v));
        }
    }
    redm[tid] = mx;
    __syncthreads();
    for (int s = 128; s > 0; s >>= 1) {
        if (tid < s) redm[tid] = fmax(redm[tid], redm[tid + s]);
        __syncthreads();
    }
    if (tid == 0)
        atomicMax((unsigned long long*)&S[20],
                  (unsigned long long)__double_as_longlong(redm[0]));
}

__global__ void k_scale(double* S) {
    unsigned long long bits = *((unsigned long long*)&S[20]);
    double mx = __longlong_as_double((long long)bits);
    S[21] = fmax(mx / 7.0, 1e-8);
}

__global__ __launch_bounds__(256) void k_quant(const double* __restrict__ Z,
                                               const double* __restrict__ S,
                                               float* __restrict__ out) {
    double scale = S[21];
    double inv = 1.0 / scale;
    int i = blockIdx.x * 256 + threadIdx.x;
    const int n = NTOK * DMODEL;
    for (; i < n; i += gridDim.x * 256) {
        double r = rint(Z[i] * inv);
        r = fmin(fmax(r, -7.0), 7.0);
        out[i] = (float)(r * scale);
    }
}

extern "C" void kernel_launch(void* const* d_in, const int* in_sizes, int n_in,
                              void* d_out, int out_size, void* d_ws, size_t ws_size,
                              hipStream_t stream) {
    if (ws_size < WS_NEED) return;

    const float* x  = (const float*)d_in[0];
    const float* Wq = (const float*)d_in[1];
    const float* bq = (const float*)d_in[2];
    const float* Wk = (const float*)d_in[3];
    const float* bk = (const float*)d_in[4];
    const float* Wv = (const float*)d_in[5];
    const float* bv = (const float*)d_in[6];
    const float* Wo = (const float*)d_in[7];
    const float* bo = (const float*)d_in[8];
    float* out = (float*)d_out;

    double* S = (double*)d_ws;
    signed char* tern = (signed char*)d_ws + OFF_TERN;
    signed char* XD = (signed char*)d_ws + OFF_XD;
    unsigned char* QDF = (unsigned char*)d_ws + OFF_QDF;
    unsigned char* KDF = (unsigned char*)d_ws + OFF_KDF;
    unsigned char* VDF = (unsigned char*)d_ws + OFF_VDF;
    double* Z = (double*)((char*)d_ws + OFF_QDF);

    k_zero_scalars<<<1, 64, 0, stream>>>(S);
    k_abssum<<<dim3(256, 4), 256, 0, stream>>>(Wq, Wk, Wv, Wo, S);
    k_delta<<<1, 64, 0, stream>>>(S);
    k_tern<<<dim3(256, 4), 256, 0, stream>>>(Wq, Wk, Wv, Wo, tern, S);
    k_alpha<<<1, 64, 0, stream>>>(S);
    k_digx<<<4096, 256, 0, stream>>>(x, XD);
    k_proji8<<<dim3(32, 16, 3), 256, 0, stream>>>(XD, tern, bq, bk, bv, QDF, KDF, VDF, S);
    k_attn<<<dim3(SEQ / 64, BATCH * NHEADS), 256, 0, stream>>>(QDF, KDF, VDF, XD);
    k_oproji8<<<dim3(32, 16), 256, 0, stream>>>(XD, tern, bo, Z, S);
    k_scale<<<1, 1, 0, stream>>>(S);
    k_quant<<<4096, 256, 0, stream>>>(Z, S, out);
}